// Round 6
// baseline (395.227 us; speedup 1.0000x reference)
//
#include <hip/hip_runtime.h>
#include <hip/hip_bf16.h>

// IO-HMM fwd/bwd chain + projection for MI355X (gfx950).
// L=256 steps, B=128 batch, S=256 states, NL=64 labels.
//
// Kernel 1 (chain): R17b = R17 (barrier-free producer/consumer-flag chain)
//   + BOUNDED poll (2^17 spins ~ 10ms >> any legitimate wait): if the flag
//   protocol ever livelocks, waves proceed with stale data -> wrong-answer
//   FAIL with counters, instead of a hang that kills the container. R17's
//   first submission died with "container failed twice" -- cause ambiguous
//   (infra flake vs hang); this build distinguishes all four outcomes.
//   Design (unchanged from R17): R12-R16 showed step ~2000cyc invariant to
//   wave geometry, LDS traffic (2x), MFMA chain depth, read pipelining,
//   prefetch depth, store placement -- the only untouched term was the
//   block-wide s_barrier convergence (period ~ slowest wave + re-accumulated
//   skew). Replaced with chunk-granular flags:
//   - 8 waves x 2 M-tiles; wave w produces carry chunk w = B-frag kt=w.
//   - producer: 2 ds_write + lgkmcnt(0) + lane0 writes flg[w]=s (monotone).
//   - consumer: batched poll of 7 remote flags >= s-1; own chunk needs no
//     flag (same-wave lgkmcnt order); consumption rotated (w, w+1, ...)
//     with a_hi PRE-ROTATED at load (static reg indices, rule #20).
//   - safety: flags >= s-1 certify all waves finished READING the s-2
//     plane (producer raises s-1 only after consuming s-2), so the
//     double-buffer overwrite is safe; max inter-wave lead = 1 step.
//   Carry layout / RNE packs / f16 single-product T / odd stride 67 / em
//   ring depth 3 / post-flag global stores unchanged. REVERT to R12 if
//   this fails again or absmax > 396.8.
// Kernel 2 (score): R11 version unchanged (gap is timed-region overhead).

typedef _Float16 half8 __attribute__((ext_vector_type(8)));
typedef _Float16 half4 __attribute__((ext_vector_type(4)));
typedef float    f32x4 __attribute__((ext_vector_type(4)));
typedef unsigned long long u64;

#define LL 256
#define BB 128
#define SS 256
#define BT 16
#define RSTR8 67   // carry/p-plane row stride in 8B units (ODD -> conflict-free)
#define RSTRO 65   // o-plane row stride in 8B units (ODD -> conflict-free)

static __device__ __forceinline__ f32x4 mfma16f(half8 a, half8 b, f32x4 c) {
  return __builtin_amdgcn_mfma_f32_16x16x32_f16(a, b, c, 0, 0, 0);
}

// LDS-only barrier: order ds ops, leave vmcnt (global loads/stores) in flight.
static __device__ __forceinline__ void lds_barrier() {
  __asm__ __volatile__("s_waitcnt lgkmcnt(0)\n\ts_barrier" ::: "memory");
}

// Round-to-nearest-even f16 pack (NOT cvt_pkrtz -- RTZ bias compounds over
// the 255-step chain into ~6% coherent shrink; R8 erratum).
static __device__ __forceinline__ u64 pack4(f32x4 v) {
  union { half4 h; u64 u; } x;
  x.h[0] = (_Float16)v[0];
  x.h[1] = (_Float16)v[1];
  x.h[2] = (_Float16)v[2];
  x.h[3] = (_Float16)v[3];
  return x.u;
}

// 16B logical fragment as two b64 reads (8B-aligned odd-stride layout).
static __device__ __forceinline__ half8 read_frag_s(const u64* plane, int row,
                                                    int kt, int q, int stride8) {
  const int o = row * stride8 + kt * 8 + q * 2;
  union { u64 u[2]; half8 v; } x;
  x.u[0] = plane[o];
  x.u[1] = plane[o + 1];
  return x.v;
}

__global__ __launch_bounds__(512, 2)
void hmm_chain(const int* __restrict__ sent, const float* __restrict__ emb,
               const float* __restrict__ T, _Float16* __restrict__ fwh,
               _Float16* __restrict__ gh)
{
  __shared__ u64 s_carry[2][BT * RSTR8]; // [buf][row*stride], single f16 plane
  __shared__ int s_tok[BT * 257];        // [batch][l], stride 257
  __shared__ int flg[8];                 // producer flags: flg[c]=s <=> chunk c
                                         // of step s is readable
  volatile int* vflg = flg;

  const int tid  = threadIdx.x;
  const int lane = tid & 63;
  const int w    = tid >> 6;   // wave 0..7 -> produces chunk w = states [32w,32w+32)
  const int m    = lane & 15;  // A row-in-tile / B col (= batch)
  const int q    = lane >> 4;  // quad

  const int  bid = blockIdx.x;
  const bool fwd = (bid < 8);
  const int  bg0 = (fwd ? bid : bid - 8) * BT;
  _Float16* const obuf = fwd ? fwh : gh;

  // ---- stage sentence tokens ----
  for (int idx = tid; idx < BT * LL; idx += 512) {
    int bb = idx >> 8, l2 = idx & 255;
    s_tok[bb * 257 + l2] = sent[(bg0 + bb) * LL + l2];
  }
  __syncthreads();

  // ---- load T fragments (A operand), 2 M-tiles x 8 K-frags,
  //      PRE-ROTATED: a_hi[t][i] holds the frag for kt=(w+i)&7, so the
  //      consumption loop uses static register indices (rule #20).
  half8 a_hi[2][8];
#pragma unroll
  for (int t = 0; t < 2; ++t) {
    const int r0 = 32 * w + 16 * t + m;    // state (M index)
#pragma unroll
    for (int i = 0; i < 8; ++i) {
      const int kt = (w + i) & 7;          // rotated k-tile (address only)
      const int kb = 32 * kt + 8 * q;      // k base
      float v[8];
      if (fwd) {
        f32x4 f0 = *(const f32x4*)(T + r0 * 256 + kb);
        f32x4 f1 = *(const f32x4*)(T + r0 * 256 + kb + 4);
#pragma unroll
        for (int j = 0; j < 4; ++j) { v[j] = f0[j]; v[4 + j] = f1[j]; }
      } else {
#pragma unroll
        for (int j = 0; j < 8; ++j) v[j] = T[(kb + j) * 256 + r0]; // T^T
      }
      half8 hi;
#pragma unroll
      for (int j = 0; j < 8; ++j) hi[j] = (_Float16)v[j];   // RNE
      a_hi[t][i] = hi;
    }
  }

  // ---- init carry at l0 + first-row store ----
  const int l0 = fwd ? 0 : (LL - 1);
  {
    const int tok0 = s_tok[m * 257 + l0];
    f32x4 one = 1.0f;
    const u64 pone = pack4(one);
#pragma unroll
    for (int t = 0; t < 2; ++t) {
      const int st = 32 * w + 16 * t + 4 * q;     // this lane's first state
      f32x4 e0 = *(const f32x4*)(emb + (size_t)tok0 * 256 + st);
      u64 pc = pack4(e0);                         // carry = em[l0] both dirs
      u64 po = fwd ? pc : pone;                   // g[L-1] = 1
      *(u64*)(obuf + (size_t)(l0 * BB + bg0 + m) * SS + st) = po;
      s_carry[0][m * RSTR8 + 8 * w + 4 * t + q] = pc;
    }
  }

  // em gather for step su (clamped), direction-mapped, tile t
  auto ldem = [&](int su, int t) -> f32x4 {
    su = su < LL ? su : LL - 1;
    const int ln = fwd ? su : (LL - 1) - su;
    const int tk = s_tok[m * 257 + ln];
    return *(const f32x4*)(emb + (size_t)tk * 256 + 32 * w + 16 * t + 4 * q);
  };

  // ---- prefetch em ring depth 3, static slots (2 tiles each) ----
  f32x4 em0a = ldem(1, 0), em0b = ldem(1, 1);
  f32x4 em1a = ldem(2, 0), em1b = ldem(2, 1);
  f32x4 em2a = ldem(3, 0), em2b = ldem(3, 1);

  // publish step-0 flags; the __syncthreads orders init-carry + flags for
  // everyone (the ONLY block barrier -- the main loop has none).
  if (lane == 0) vflg[w] = 0;
  __syncthreads();

  // one chain step: consume (ea,eb) = em for step ss, refill with em(ss+3).
  auto step = [&](int ss, f32x4& ea, f32x4& eb) {
    const int l   = fwd ? ss : (LL - 1) - ss;
    const int sm1 = ss - 1;
    const int rb  = (ss - 1) & 1, wb = ss & 1;
    const u64* pr = &s_carry[rb][0];

    // ---- BOUNDED batched poll: the 7 remote chunks of step ss-1 ready?
    // (also certifies all waves finished READING step ss-2 -> our write
    //  below may safely overwrite that plane). Spin cap 2^17 (~10ms) is a
    //  livelock detector: on trigger we proceed with stale data -> harness
    //  reports a wrong-answer FAIL (with counters) instead of a dead
    //  container. Never triggers if the protocol is sound (step ~2000cyc).
    {
      int ok = 0;
      for (int spin = 0; spin < (1 << 17); ++spin) {
        int f1 = vflg[(w + 1) & 7], f2 = vflg[(w + 2) & 7];
        int f3 = vflg[(w + 3) & 7], f4 = vflg[(w + 4) & 7];
        int f5 = vflg[(w + 5) & 7], f6 = vflg[(w + 6) & 7];
        int f7 = vflg[(w + 7) & 7];
        ok = (f1 >= sm1) & (f2 >= sm1) & (f3 >= sm1) & (f4 >= sm1) &
             (f5 >= sm1) & (f6 >= sm1) & (f7 >= sm1);
        if (ok) break;
        __builtin_amdgcn_s_sleep(1);
      }
    }

    // ---- reads + MFMAs, chunk order w, w+1, ... (a_hi pre-rotated).
    // Own chunk (i=0) ordered by same-wave lgkmcnt, no flag needed.
    half8 b0 = read_frag_s(pr, m, (w + 0) & 7, q, RSTR8);
    half8 b1 = read_frag_s(pr, m, (w + 1) & 7, q, RSTR8);
    half8 b2 = read_frag_s(pr, m, (w + 2) & 7, q, RSTR8);
    half8 b3 = read_frag_s(pr, m, (w + 3) & 7, q, RSTR8);

    f32x4 e0 = ea, e1 = eb;
    ea = ldem(ss + 3, 0);                // deep prefetch (3 steps ahead)
    eb = ldem(ss + 3, 1);

    f32x4 aA0 = 0.0f, aB0 = 0.0f, aA1 = 0.0f, aB1 = 0.0f;
    aA0 = mfma16f(a_hi[0][0], b0, aA0);
    aA1 = mfma16f(a_hi[1][0], b0, aA1);
    b0 = read_frag_s(pr, m, (w + 4) & 7, q, RSTR8);
    aB0 = mfma16f(a_hi[0][1], b1, aB0);
    aB1 = mfma16f(a_hi[1][1], b1, aB1);
    b1 = read_frag_s(pr, m, (w + 5) & 7, q, RSTR8);
    aA0 = mfma16f(a_hi[0][2], b2, aA0);
    aA1 = mfma16f(a_hi[1][2], b2, aA1);
    b2 = read_frag_s(pr, m, (w + 6) & 7, q, RSTR8);
    aB0 = mfma16f(a_hi[0][3], b3, aB0);
    aB1 = mfma16f(a_hi[1][3], b3, aB1);
    b3 = read_frag_s(pr, m, (w + 7) & 7, q, RSTR8);
    aA0 = mfma16f(a_hi[0][4], b0, aA0);
    aA1 = mfma16f(a_hi[1][4], b0, aA1);
    aB0 = mfma16f(a_hi[0][5], b1, aB0);
    aB1 = mfma16f(a_hi[1][5], b1, aB1);
    aA0 = mfma16f(a_hi[0][6], b2, aA0);
    aA1 = mfma16f(a_hi[1][6], b2, aA1);
    aB0 = mfma16f(a_hi[0][7], b3, aB0);
    aB1 = mfma16f(a_hi[1][7], b3, aB1);

    f32x4 v0 = aA0 + aB0, v1 = aA1 + aB1;   // pre-em matmul results
    f32x4 cn0 = v0 * e0,  cn1 = v1 * e1;    // new carry

    u64 p0 = pack4(cn0), p1 = pack4(cn1);
    s_carry[wb][m * RSTR8 + 8 * w + q]     = p0;
    s_carry[wb][m * RSTR8 + 8 * w + 4 + q] = p1;
    // drain our data writes, then publish the flag
    __asm__ __volatile__("s_waitcnt lgkmcnt(0)" ::: "memory");
    if (lane == 0) vflg[w] = ss;

    // global stores post-flag: off the serial path, reg-only inputs
    u64 sv0 = fwd ? p0 : pack4(v0);
    u64 sv1 = fwd ? p1 : pack4(v1);
    const int st0 = 32 * w + 4 * q;
    _Float16* orow = obuf + (size_t)(l * BB + bg0 + m) * SS;
    *(u64*)(orow + st0)      = sv0;
    *(u64*)(orow + st0 + 16) = sv1;
  };

  // ---- main chain: 255 steps = 85 x 3 (static ring slots, no tail) ----
  for (int s = 1; s < LL; s += 3) {
    step(s + 0, em0a, em0b);
    step(s + 1, em1a, em1b);
    step(s + 2, em2a, em2b);
  }
}

__global__ __launch_bounds__(256, 2)
void hmm_score(const _Float16* __restrict__ fwh, const _Float16* __restrict__ gh,
               const float* __restrict__ outm, float* __restrict__ score)
{
  __shared__ u64 p_pl[64 * RSTR8];   // p = fw*g, [row][k] f16
  __shared__ u64 o_pl[64 * RSTRO];   // outm^T,   [n][k]  f16

  const int tid  = threadIdx.x;
  const int lane = tid & 63;
  const int w    = tid >> 6;
  const int rh   = w >> 1;     // row half: rows [32rh, 32rh+32)
  const int np   = w & 1;      // n-pair: n-tiles {2np, 2np+1}
  const int m    = lane & 15;
  const int q    = lane >> 4;
  const int R0   = blockIdx.x * 64;  // row = l*128 + b

  // ---- stage outm -> o_pl[n][k] f16 (RNE, hi only), coalesced f32x4 loads
  {
    _Float16* o_h = (_Float16*)o_pl;
    for (int i = tid; i < 4096; i += 256) {
      f32x4 v = *(const f32x4*)(outm + i * 4);   // flat = k*64+n
      int k = i >> 4, n0 = (i & 15) * 4;
#pragma unroll
      for (int r = 0; r < 4; ++r)
        o_h[(n0 + r) * (RSTRO * 4) + k] = (_Float16)v[r];
    }
  }

  // ---- stage p = fw * g (f16 packed mul, RNE) ----
  for (int idx = tid; idx < 64 * 64; idx += 256) {
    int row = idx >> 6, c = idx & 63;       // c = 8B column index
    union { u64 u; half4 h; } a, b, p;
    a.u = *(const u64*)(fwh + (size_t)(R0 + row) * 256 + c * 4);
    b.u = *(const u64*)(gh  + (size_t)(R0 + row) * 256 + c * 4);
    p.h = a.h * b.h;                        // v_pk_mul_f16 x2
    p_pl[row * RSTR8 + c] = p.u;
  }
  lds_barrier();

  f32x4 acc[2][2];
#pragma unroll
  for (int j = 0; j < 2; ++j)
#pragma unroll
    for (int jn = 0; jn < 2; ++jn) acc[j][jn] = 0.0f;

#pragma unroll
  for (int kt = 0; kt < 8; ++kt) {
    half8 of[2];
#pragma unroll
    for (int jn = 0; jn < 2; ++jn)
      of[jn] = read_frag_s(o_pl, 16 * (2 * np + jn) + m, kt, q, RSTRO);
#pragma unroll
    for (int j = 0; j < 2; ++j) {
      half8 pf = read_frag_s(p_pl, 32 * rh + 16 * j + m, kt, q, RSTR8);
#pragma unroll
      for (int jn = 0; jn < 2; ++jn)
        acc[j][jn] = mfma16f(pf, of[jn], acc[j][jn]);
    }
  }

#pragma unroll
  for (int j = 0; j < 2; ++j) {
#pragma unroll
    for (int jn = 0; jn < 2; ++jn) {
#pragma unroll
      for (int r = 0; r < 4; ++r) {
        int row = R0 + 32 * rh + 16 * j + 4 * q + r;
        int l = row >> 7, b = row & 127;
        score[(size_t)b * 16384 + l * 64 + 16 * (2 * np + jn) + m] = acc[j][jn][r];
      }
    }
  }
}

extern "C" void kernel_launch(void* const* d_in, const int* in_sizes, int n_in,
                              void* d_out, int out_size, void* d_ws, size_t ws_size,
                              hipStream_t stream) {
  (void)in_sizes; (void)n_in; (void)out_size; (void)ws_size;
  const int*   sent = (const int*)d_in[0];
  const float* emb  = (const float*)d_in[1];
  const float* T    = (const float*)d_in[2];
  const float* outm = (const float*)d_in[3];
  _Float16* fwh = (_Float16*)d_ws;                  // [L][B][S] f16, 16 MB
  _Float16* gh  = fwh + (size_t)LL * BB * SS;       // [L][B][S] f16, 16 MB

  hmm_chain<<<16, 512, 0, stream>>>(sent, emb, T, fwh, gh);
  hmm_score<<<512, 256, 0, stream>>>(fwh, gh, outm, (float*)d_out);
}

// Round 8
// 262.122 us; speedup vs baseline: 1.5078x; 1.5078x over previous
//
#include <hip/hip_runtime.h>
#include <hip/hip_bf16.h>

// IO-HMM fwd/bwd chain + projection for MI355X (gfx950).
// L=256 steps, B=128 batch, S=256 states, NL=64 labels.
//
// Kernel 1 (chain): R18b = R18 (R12 geometry + coalesced deferred output
//   stores) with the bwd-init bug fixed. R18's FAIL (absmax 27328) was NOT
//   the theory failing: at s=1 the bwd deferred store wrote row l=255 from
//   v_pl[0], which was never initialized, clobbering g[255]=1 with garbage.
//   Fix: v_pl[0] initialized to pack4(1.0) in the init phase (each thread
//   writes its own slot -> full coverage); the init-row global store is
//   dropped (s=1 deferred store now covers l0 for both directions; fwd
//   reads s_carry[0] which always was initialized).
//   Theory under test (unchanged): the per-step global SCATTER store
//   (64 lanes x 512B stride = 16 lines/instr, 32B partial-line L2 RMW;
//   in-order vmcnt retire chains each step's em-consume behind the prev
//   step's store tail) is the last untested component of the ~2000cyc
//   step floor. R18b stores wave w's batch-row as ONE lane-linear 512B
//   store (8 full lines), deferred one step. Stored bits identical to R12.
//   If neutral: invariance table complete -> declare structural ceiling.
// Kernel 2 (score): R11 version unchanged (gap is timed-region overhead).

typedef _Float16 half8 __attribute__((ext_vector_type(8)));
typedef _Float16 half4 __attribute__((ext_vector_type(4)));
typedef float    f32x4 __attribute__((ext_vector_type(4)));
typedef unsigned long long u64;

#define LL 256
#define BB 128
#define SS 256
#define BT 16
#define RSTR8 67   // carry/p-plane row stride in 8B units (ODD -> conflict-free)
#define RSTRO 65   // o-plane row stride in 8B units (ODD -> conflict-free)

static __device__ __forceinline__ f32x4 mfma16f(half8 a, half8 b, f32x4 c) {
  return __builtin_amdgcn_mfma_f32_16x16x32_f16(a, b, c, 0, 0, 0);
}

// LDS-only barrier: order ds ops, leave vmcnt (global loads/stores) in flight.
static __device__ __forceinline__ void lds_barrier() {
  __asm__ __volatile__("s_waitcnt lgkmcnt(0)\n\ts_barrier" ::: "memory");
}

// Round-to-nearest-even f16 pack (NOT cvt_pkrtz -- RTZ bias compounds over
// the 255-step chain into ~6% coherent shrink; R8 erratum).
static __device__ __forceinline__ u64 pack4(f32x4 v) {
  union { half4 h; u64 u; } x;
  x.h[0] = (_Float16)v[0];
  x.h[1] = (_Float16)v[1];
  x.h[2] = (_Float16)v[2];
  x.h[3] = (_Float16)v[3];
  return x.u;
}

// 16B logical fragment as two b64 reads (8B-aligned odd-stride layout).
static __device__ __forceinline__ half8 read_frag_s(const u64* plane, int row,
                                                    int kt, int q, int stride8) {
  const int o = row * stride8 + kt * 8 + q * 2;
  union { u64 u[2]; half8 v; } x;
  x.u[0] = plane[o];
  x.u[1] = plane[o + 1];
  return x.v;
}

__global__ __launch_bounds__(1024, 4)
void hmm_chain(const int* __restrict__ sent, const float* __restrict__ emb,
               const float* __restrict__ T, _Float16* __restrict__ fwh,
               _Float16* __restrict__ gh)
{
  __shared__ u64 s_carry[2][BT * RSTR8]; // [buf][row*stride], single f16 plane
  __shared__ u64 v_pl[2][BT * RSTR8];    // bwd: pack4(v) mirror plane, dbuf
  __shared__ int s_tok[BT * 257];        // [batch][l], stride 257

  const int tid  = threadIdx.x;
  const int lane = tid & 63;
  const int w    = tid >> 6;   // wave 0..15 -> states [16w, 16w+16)
  const int m    = lane & 15;  // A row-in-tile / B col (= batch)
  const int q    = lane >> 4;  // quad

  const int  bid = blockIdx.x;
  const bool fwd = (bid < 8);
  const int  bg0 = (fwd ? bid : bid - 8) * BT;
  _Float16* const obuf = fwd ? fwh : gh;
  const int  st  = 16 * w + 4 * q;       // this lane's first state

  // ---- stage sentence tokens ----
  for (int idx = tid; idx < BT * LL; idx += 1024) {
    int bb = idx >> 8, l2 = idx & 255;
    s_tok[bb * 257 + l2] = sent[(bg0 + bb) * LL + l2];
  }
  __syncthreads();

  // ---- load T fragments (A operand), single f16: 8 frags = 32 regs
  half8 a_hi[8];
#pragma unroll
  for (int kt = 0; kt < 8; ++kt) {
    const int r0 = 16 * w + m;           // state (M index)
    const int kb = 32 * kt + 8 * q;      // k base
    float v[8];
    if (fwd) {
      f32x4 f0 = *(const f32x4*)(T + r0 * 256 + kb);
      f32x4 f1 = *(const f32x4*)(T + r0 * 256 + kb + 4);
#pragma unroll
      for (int j = 0; j < 4; ++j) { v[j] = f0[j]; v[4 + j] = f1[j]; }
    } else {
#pragma unroll
      for (int j = 0; j < 8; ++j) v[j] = T[(kb + j) * 256 + r0]; // T^T
    }
    half8 hi;
#pragma unroll
    for (int j = 0; j < 8; ++j) hi[j] = (_Float16)v[j];   // RNE
    a_hi[kt] = hi;
  }

  // ---- init carry at l0; bwd also inits v_pl[0] = 1 (step-0 output g[l0])
  const int l0 = fwd ? 0 : (LL - 1);
  {
    const int tok0 = s_tok[m * 257 + l0];
    f32x4 e0 = *(const f32x4*)(emb + (size_t)tok0 * 256 + st);
    u64 pc = pack4(e0);                       // carry = em[l0] both dirs
    s_carry[0][m * RSTR8 + 4 * w + q] = pc;
    if (!fwd) {
      f32x4 one = 1.0f;
      v_pl[0][m * RSTR8 + 4 * w + q] = pack4(one);  // g[L-1] = 1
    }
  }

  // ---- prefetch em for step 1 ----
  f32x4 em_pref;
  {
    const int l1 = fwd ? 1 : (LL - 2);
    const int tok1 = s_tok[m * 257 + l1];
    em_pref = *(const f32x4*)(emb + (size_t)tok1 * 256 + st);
  }
  __syncthreads();

  // ---- main chain ----
  // Step s's output row for step s-1 is stored COALESCED: wave w reads
  // batch-row w of the s-1 output plane (fwd: carry; bwd: v_pl) lane-linear
  // (lane c holds states 4c..4c+3) and issues ONE 512B store (8 full lines).
  for (int s = 1; s < LL; ++s) {
    const int lp = fwd ? (s - 1) : (LL - s);   // prev step's l
    const int rb = (s - 1) & 1, wb = s & 1;

    const u64* pr = &s_carry[rb][0];
    half8 bfr[8];
#pragma unroll
    for (int kt = 0; kt < 8; ++kt)
      bfr[kt] = read_frag_s(pr, m, kt, q, RSTR8);

    // deferred out-row read for step s-1 (coalesced store issued below)
    const u64* op = fwd ? &s_carry[rb][0] : &v_pl[rb][0];
    u64 ov = op[w * RSTR8 + lane];

    // consume prefetched em; issue next prefetch (token from LDS)
    f32x4 em_now = em_pref;
    {
      const int ln = fwd ? (s + 1 < LL ? s + 1 : LL - 1)
                         : ((LL - 2) - s > 0 ? (LL - 2) - s : 0);
      const int tokn = s_tok[m * 257 + ln];
      em_pref = *(const f32x4*)(emb + (size_t)tokn * 256 + st);
    }

    // single-product f16 matmul (8 MFMA/wave/step)
    f32x4 hh = 0.0f;
#pragma unroll
    for (int kt = 0; kt < 8; ++kt)
      hh = mfma16f(a_hi[kt], bfr[kt], hh);
    f32x4 v  = hh;                     // pre-em matmul result
    f32x4 cn = v * em_now;             // new carry

    u64 p0 = pack4(cn);
    s_carry[wb][m * RSTR8 + 4 * w + q] = p0;
    if (!fwd)
      v_pl[wb][m * RSTR8 + 4 * w + q] = pack4(v);  // g[l] = v (bit-identical)

    // coalesced 512B store of the previous step's row (8 full lines)
    *(u64*)(obuf + ((size_t)lp * BB + bg0 + w) * SS + lane * 4) = ov;

    lds_barrier();  // LDS ordering only; global stores/loads stay in flight
  }

  // ---- epilogue: store the final step's row (plane 1 = step 255) ----
  {
    const int lp = fwd ? (LL - 1) : 0;
    const u64* op = fwd ? &s_carry[1][0] : &v_pl[1][0];
    u64 ov = op[w * RSTR8 + lane];
    *(u64*)(obuf + ((size_t)lp * BB + bg0 + w) * SS + lane * 4) = ov;
  }
}

__global__ __launch_bounds__(256, 2)
void hmm_score(const _Float16* __restrict__ fwh, const _Float16* __restrict__ gh,
               const float* __restrict__ outm, float* __restrict__ score)
{
  __shared__ u64 p_pl[64 * RSTR8];   // p = fw*g, [row][k] f16
  __shared__ u64 o_pl[64 * RSTRO];   // outm^T,   [n][k]  f16

  const int tid  = threadIdx.x;
  const int lane = tid & 63;
  const int w    = tid >> 6;
  const int rh   = w >> 1;     // row half: rows [32rh, 32rh+32)
  const int np   = w & 1;      // n-pair: n-tiles {2np, 2np+1}
  const int m    = lane & 15;
  const int q    = lane >> 4;
  const int R0   = blockIdx.x * 64;  // row = l*128 + b

  // ---- stage outm -> o_pl[n][k] f16 (RNE, hi only), coalesced f32x4 loads
  {
    _Float16* o_h = (_Float16*)o_pl;
    for (int i = tid; i < 4096; i += 256) {
      f32x4 v = *(const f32x4*)(outm + i * 4);   // flat = k*64+n
      int k = i >> 4, n0 = (i & 15) * 4;
#pragma unroll
      for (int r = 0; r < 4; ++r)
        o_h[(n0 + r) * (RSTRO * 4) + k] = (_Float16)v[r];
    }
  }

  // ---- stage p = fw * g (f16 packed mul, RNE) ----
  for (int idx = tid; idx < 64 * 64; idx += 256) {
    int row = idx >> 6, c = idx & 63;       // c = 8B column index
    union { u64 u; half4 h; } a, b, p;
    a.u = *(const u64*)(fwh + (size_t)(R0 + row) * 256 + c * 4);
    b.u = *(const u64*)(gh  + (size_t)(R0 + row) * 256 + c * 4);
    p.h = a.h * b.h;                        // v_pk_mul_f16 x2
    p_pl[row * RSTR8 + c] = p.u;
  }
  lds_barrier();

  f32x4 acc[2][2];
#pragma unroll
  for (int j = 0; j < 2; ++j)
#pragma unroll
    for (int jn = 0; jn < 2; ++jn) acc[j][jn] = 0.0f;

#pragma unroll
  for (int kt = 0; kt < 8; ++kt) {
    half8 of[2];
#pragma unroll
    for (int jn = 0; jn < 2; ++jn)
      of[jn] = read_frag_s(o_pl, 16 * (2 * np + jn) + m, kt, q, RSTRO);
#pragma unroll
    for (int j = 0; j < 2; ++j) {
      half8 pf = read_frag_s(p_pl, 32 * rh + 16 * j + m, kt, q, RSTR8);
#pragma unroll
      for (int jn = 0; jn < 2; ++jn)
        acc[j][jn] = mfma16f(pf, of[jn], acc[j][jn]);
    }
  }

#pragma unroll
  for (int j = 0; j < 2; ++j) {
#pragma unroll
    for (int jn = 0; jn < 2; ++jn) {
#pragma unroll
      for (int r = 0; r < 4; ++r) {
        int row = R0 + 32 * rh + 16 * j + 4 * q + r;
        int l = row >> 7, b = row & 127;
        score[(size_t)b * 16384 + l * 64 + 16 * (2 * np + jn) + m] = acc[j][jn][r];
      }
    }
  }
}

extern "C" void kernel_launch(void* const* d_in, const int* in_sizes, int n_in,
                              void* d_out, int out_size, void* d_ws, size_t ws_size,
                              hipStream_t stream) {
  (void)in_sizes; (void)n_in; (void)out_size; (void)ws_size;
  const int*   sent = (const int*)d_in[0];
  const float* emb  = (const float*)d_in[1];
  const float* T    = (const float*)d_in[2];
  const float* outm = (const float*)d_in[3];
  _Float16* fwh = (_Float16*)d_ws;                  // [L][B][S] f16, 16 MB
  _Float16* gh  = fwh + (size_t)LL * BB * SS;       // [L][B][S] f16, 16 MB

  hmm_chain<<<16, 1024, 0, stream>>>(sent, emb, T, fwh, gh);
  hmm_score<<<512, 256, 0, stream>>>(fwh, gh, outm, (float*)d_out);
}